// Round 9
// baseline (10178.059 us; speedup 1.0000x reference)
//
#include <hip/hip_runtime.h>
#include <hip/hip_bf16.h>

// Problem constants (B=1)
#define S_LEN 4096
#define HID 2048
#define NH 16
#define NKV 4
#define HD 128        // D
#define MSK 32        // M (sketch dim)
#define KTOP 8
#define NBLK 64       // S/BLK
#define NEGV -1000000000.0f
#define SENT -3.0e38f   // finite "minus infinity" sentinel (fast-math safe)
#define CH 256          // q/attn row-chunk
#define NCH (S_LEN / CH)

typedef __hip_bfloat16 bf16;

// EMPIRICAL (R1-R8): inputs are FP32; OUTPUT dtype is the reference's output
// dtype = FP32 (the "(bf16)" in the test label is a hardcoded string; the
// uint16<<16 readout in the traceback is a dead branch). R4-R8's absmax
// 3.914 == sqrt(2)*2.797: bf16-written output decoded as fp32 produced a
// decorrelated-but-correct-scale comparison. Fix: store fp32 to d_out.

// Bit-level NaN/Inf flush — cannot be folded away by fast-math.
__device__ __forceinline__ float sanf(float v) {
    unsigned u = __float_as_uint(v);
    return ((u & 0x7f800000u) == 0x7f800000u) ? 0.f : v;
}
__device__ __forceinline__ float toF(const float* p, size_t i) { return sanf(p[i]); }
__device__ __forceinline__ float toF(const bf16* p, size_t i) { return sanf(__bfloat162float(p[i])); }
__device__ __forceinline__ float ldb(const bf16* p) { return sanf(__bfloat162float(*p)); }
__device__ __forceinline__ void stb(bf16* p, float v) { *p = __float2bfloat16(sanf(v)); }
__device__ __forceinline__ void stc(bf16* p, float v) { *p = __float2bfloat16(sanf(v)); }
__device__ __forceinline__ void stc(float* p, float v) { *p = sanf(v); }

// ---------------------------------------------------------------------------
// FUSED projection + RoPE + block-sketch (fp32 selection path).
// One block per (head h, local row-block by): global rows m0g..m0g+63.
// Writes roped bf16 tile to Xout at CHUNK-LOCAL rows, sketch to Sout at
// GLOBAL block index. For K: r0=0, full grid -> local == global.
// ---------------------------------------------------------------------------
__global__ __launch_bounds__(256) void proj_rope_sketch(
    const float* __restrict__ A,      // hidden [S, 2048] fp32
    const float* __restrict__ W,      // [2048, nheads*128] fp32
    const int* __restrict__ pos_ids,
    const float* __restrict__ H,      // [128, 32] fp32
    bf16* __restrict__ Xout,          // [rows_local, nheads*128] roped bf16
    float* __restrict__ Sout,         // [nheads][NBLK][MSK] (global)
    int nheads, int r0) {
    const int h = blockIdx.x;
    const int m0g = r0 + blockIdx.y * 64;   // global row base
    const int m0l = blockIdx.y * 64;        // chunk-local row base
    const int Nd = nheads * HD;
    const int t = threadIdx.x;
    const int tx = t & 31, ty = t >> 5;     // tx: 4-col group, ty: 8-row group

    __shared__ float As[16][65];
    __shared__ float Ws[16][129];
    __shared__ float Rt[64][129];
    __shared__ float Hs[128][33];
    __shared__ float red[32][9];

    float acc[8][4];
#pragma unroll
    for (int i = 0; i < 8; i++)
#pragma unroll
        for (int j = 0; j < 4; j++) acc[i][j] = 0.f;

    for (int k0 = 0; k0 < HID; k0 += 16) {
#pragma unroll
        for (int i = 0; i < 4; i++) {          // 64 rows x 16 k
            int e = t + i * 256;
            int m = e >> 4, kk = e & 15;
            As[kk][m] = toF(A, (size_t)(m0g + m) * HID + k0 + kk);
        }
#pragma unroll
        for (int i = 0; i < 8; i++) {          // 16 k x 128 cols
            int e = t + i * 256;
            int kk = e >> 7, n = e & 127;
            Ws[kk][n] = toF(W, (size_t)(k0 + kk) * Nd + h * HD + n);
        }
        __syncthreads();
#pragma unroll
        for (int kk = 0; kk < 16; kk++) {
            float a[8], b[4];
#pragma unroll
            for (int i = 0; i < 8; i++) a[i] = As[kk][ty * 8 + i];
#pragma unroll
            for (int j = 0; j < 4; j++) b[j] = Ws[kk][tx * 4 + j];
#pragma unroll
            for (int i = 0; i < 8; i++)
#pragma unroll
                for (int j = 0; j < 4; j++) acc[i][j] += a[i] * b[j];
        }
        __syncthreads();
    }

    // Stage pre-rope fp32 tile
#pragma unroll
    for (int i = 0; i < 8; i++)
#pragma unroll
        for (int j = 0; j < 4; j++) Rt[ty * 8 + i][tx * 4 + j] = acc[i][j];
    __syncthreads();

    // RoPE in fp32: out[col<64] = x1*c - x2*s ; out[col>=64] = x2*c + x1*s
    float rp[8][4];
#pragma unroll
    for (int j = 0; j < 4; j++) {
        const int col = tx * 4 + j;
        const int jj = col & 63;
        const float invf = 1.0f / powf(10000.0f, (float)jj * (1.0f / 64.0f));
#pragma unroll
        for (int i = 0; i < 8; i++) {
            const int row = ty * 8 + i;
            float fr = (float)pos_ids[m0g + row] * invf;
            float c = cosf(fr), s = sinf(fr);
            float partner = Rt[row][col ^ 64];
            rp[i][j] = (col < 64) ? (acc[i][j] * c - partner * s)
                                  : (acc[i][j] * c + partner * s);
        }
    }
    __syncthreads();   // all partner reads done before in-place write

    // Write roped fp32 back to Rt (sketch path) + bf16 to global (attn path)
#pragma unroll
    for (int i = 0; i < 8; i++)
#pragma unroll
        for (int j = 0; j < 4; j++) {
            const int row = ty * 8 + i, col = tx * 4 + j;
            Rt[row][col] = rp[i][j];
            stb(&Xout[(size_t)(m0l + row) * Nd + h * HD + col], rp[i][j]);
        }
    for (int e = t; e < 128 * 32; e += 256)
        Hs[e >> 5][e & 31] = toF(H, e);
    __syncthreads();

    // Sketch: thread (m = t&31, g = t>>5) sums rows g*8..g*8+7; LDS reduce.
    {
        const int m = t & 31, g = t >> 5;
        float s = 0.f;
        for (int r = g * 8; r < g * 8 + 8; r++) {
            float part = 0.f;
            for (int d = 0; d < 128; d++) part += Rt[r][d] * Hs[d][m];
            s += part;
        }
        red[m][g] = s;
    }
    __syncthreads();
    if (t < 32) {
        float s2 = 0.f;
        for (int i = 0; i < 8; i++) s2 += red[t][i];
        Sout[((size_t)h * NBLK + (m0g >> 6)) * MSK + t] = sanf(s2 * (1.0f / 64.0f));
    }
}

// ---------------------------------------------------------------------------
// GEMM: C[cRow0+m, n] = sum_k A[m,k]*W[k,n]. A rows grid-local; C dtype
// templated (bf16 for internal v, FP32 for the final output).
// 64x64 tile, 256 threads, 4x4/thread, k-chunk 16, fp32 accumulate.
// ---------------------------------------------------------------------------
template <typename AT, typename WT, typename CT>
__global__ __launch_bounds__(256) void gemm_t(const AT* __restrict__ A,
                                              const WT* __restrict__ W,
                                              CT* __restrict__ C,
                                              int Ndim, int Kdim, int cRow0) {
    __shared__ float As[16][65];
    __shared__ float Bs[16][65];
    const int n0 = blockIdx.x * 64;
    const int m0 = blockIdx.y * 64;
    const int t = threadIdx.x;
    const int tx = t & 15, ty = t >> 4;
    float acc[4][4];
#pragma unroll
    for (int i = 0; i < 4; i++)
#pragma unroll
        for (int j = 0; j < 4; j++) acc[i][j] = 0.f;

    for (int k0 = 0; k0 < Kdim; k0 += 16) {
#pragma unroll
        for (int i = 0; i < 4; i++) {
            int e = t + i * 256;
            int m = e >> 4, kk = e & 15;
            As[kk][m] = toF(A, (size_t)(m0 + m) * Kdim + k0 + kk);
        }
#pragma unroll
        for (int i = 0; i < 4; i++) {
            int e = t + i * 256;
            int kk = e >> 6, n = e & 63;
            Bs[kk][n] = toF(W, (size_t)(k0 + kk) * Ndim + n0 + n);
        }
        __syncthreads();
#pragma unroll
        for (int kk = 0; kk < 16; kk++) {
            float a[4], b[4];
#pragma unroll
            for (int i = 0; i < 4; i++) a[i] = As[kk][ty * 4 + i];
#pragma unroll
            for (int j = 0; j < 4; j++) b[j] = Bs[kk][tx * 4 + j];
#pragma unroll
            for (int i = 0; i < 4; i++)
#pragma unroll
                for (int j = 0; j < 4; j++) acc[i][j] += a[i] * b[j];
        }
        __syncthreads();
    }
#pragma unroll
    for (int i = 0; i < 4; i++)
#pragma unroll
        for (int j = 0; j < 4; j++)
            stc(&C[(size_t)(cRow0 + m0 + ty * 4 + i) * Ndim + n0 + tx * 4 + j], acc[i][j]);
}

// ---------------------------------------------------------------------------
// Block scores + top-8 for q-blocks i = i0 + bx. One block per (bx, h),
// 64 threads. Tie-break = lowest index (matches lax.top_k).
// ---------------------------------------------------------------------------
__global__ __launch_bounds__(64) void topk_kernel(const float* __restrict__ Sq,
                                                  const float* __restrict__ Sk,
                                                  int* __restrict__ topk, int i0) {
    const int i = i0 + blockIdx.x, h = blockIdx.y, kv = h >> 2;
    const int j = threadIdx.x;
    __shared__ float vals[64];
    float v;
    if (j > i) v = NEGV;
    else if (j == i) v = 1e9f;
    else {
        v = 0.f;
        const float* sq = Sq + ((size_t)h * NBLK + i) * MSK;
        const float* sk = Sk + ((size_t)kv * NBLK + j) * MSK;
        for (int m = 0; m < MSK; m++) v += sanf(sq[m]) * sanf(sk[m]);
    }
    vals[j] = sanf(v);
    __syncthreads();
    if (j == 0) {
        for (int kk = 0; kk < KTOP; kk++) {
            float best = SENT; int bi = 0;
            for (int jj = 0; jj < 64; jj++)
                if (vals[jj] > best) { best = vals[jj]; bi = jj; }
            vals[bi] = SENT;
            topk[((size_t)h * NBLK + i) * KTOP + kk] = bi;
        }
    }
}

// ---------------------------------------------------------------------------
// Sparse attention, online softmax, CHUNKED rows [r0, r0+CH).
// q_c is CHUNK-LOCAL. One block per (local qblk, head, half). Writes attn_c
// (chunk-local). All sentinels finite; exp args finite <= 0 structurally.
// ---------------------------------------------------------------------------
__global__ __launch_bounds__(256) void attn_kernel(const bf16* __restrict__ q_c,
                                                   const bf16* __restrict__ kf,
                                                   const bf16* __restrict__ vf,
                                                   const int* __restrict__ topk,
                                                   bf16* __restrict__ attn_c, int r0) {
    const int qbg = (r0 >> 6) + blockIdx.x;   // global q block
    const int h = blockIdx.y, half = blockIdx.z;
    const int kvh = h >> 2;
    const int t = threadIdx.x;
    const int r = t & 31, g = t >> 5;
    __shared__ float Qs[32][129];
    __shared__ float KVs[64][129];
    __shared__ float Ss[32][65];
    __shared__ float mL[32], lL[32], aL[32];
    const int qrow0 = qbg * 64 + half * 32;   // global row base
    const int lrow0 = qrow0 - r0;             // chunk-local row base

    for (int e = t; e < 32 * 128; e += 256) {
        int rr = e >> 7, d = e & 127;
        Qs[rr][d] = ldb(&q_c[(size_t)(lrow0 + rr) * (NH * HD) + h * HD + d]) * 0.08838834764831845f;
    }
    if (t < 32) { mL[t] = -1.0e30f; lL[t] = 0.f; }
    float O[16];
#pragma unroll
    for (int c = 0; c < 16; c++) O[c] = 0.f;
    const int c0 = g * 16;
    const int* sel = topk + ((size_t)h * NBLK + qbg) * KTOP;

    for (int kb = 0; kb < KTOP; kb++) {
        const int blk = sel[kb] & 63;
        __syncthreads();   // (A) prev PV done (and Qs/mL staged on iter 0)
        for (int e = t; e < 64 * 128; e += 256) {
            int rr = e >> 7, d = e & 127;
            KVs[rr][d] = ldb(&kf[(size_t)(blk * 64 + rr) * (NKV * HD) + kvh * HD + d]);
        }
        __syncthreads();   // (B)
        float sc[8];
#pragma unroll
        for (int jj = 0; jj < 8; jj++) sc[jj] = 0.f;
        for (int d = 0; d < 128; d++) {
            float qv = Qs[r][d];
#pragma unroll
            for (int jj = 0; jj < 8; jj++) sc[jj] += qv * KVs[g * 8 + jj][d];
        }
        const int qpos = qrow0 + r;
#pragma unroll
        for (int jj = 0; jj < 8; jj++) {
            int j = g * 8 + jj;
            int kpos = blk * 64 + j;
            Ss[r][j] = (kpos <= qpos) ? sanf(sc[jj]) : NEGV;
        }
        __syncthreads();   // (C) all K reads + score writes done
        for (int e = t; e < 64 * 128; e += 256) {   // stage V over K
            int rr = e >> 7, d = e & 127;
            KVs[rr][d] = ldb(&vf[(size_t)(blk * 64 + rr) * (NKV * HD) + kvh * HD + d]);
        }
        if (t < 32) {
            const int row = t;
            float mb = SENT;
            for (int j = 0; j < 64; j++) mb = fmaxf(mb, Ss[row][j]);
            float mnew = fmaxf(mL[row], mb);
            float al = expf(mL[row] - mnew);
            float sum = 0.f;
            for (int j = 0; j < 64; j++) {
                float p = expf(Ss[row][j] - mnew);
                Ss[row][j] = p;
                sum += p;
            }
            lL[row] = lL[row] * al + sum;
            mL[row] = mnew;
            aL[row] = al;
        }
        __syncthreads();   // (D)
        float al = aL[r];
#pragma unroll
        for (int c = 0; c < 16; c++) O[c] *= al;
        for (int j = 0; j < 64; j++) {
            float p = Ss[r][j];
#pragma unroll
            for (int c = 0; c < 16; c++) O[c] += p * KVs[j][c0 + c];
        }
    }
    float inv_l = 1.0f / lL[r];   // lL >= 1 structurally (diag block = sel[0])
#pragma unroll
    for (int c = 0; c < 16; c++)
        stb(&attn_c[(size_t)(lrow0 + r) * (NH * HD) + h * HD + c0 + c], O[c] * inv_l);
}

// ---------------------------------------------------------------------------
extern "C" void kernel_launch(void* const* d_in, const int* in_sizes, int n_in,
                              void* d_out, int out_size, void* d_ws, size_t ws_size,
                              hipStream_t stream) {
    // Defensive pointer resolution (dict order vs sorted-key order).
    const void *p_hid, *p_pos, *p_wq, *p_wk, *p_wv, *p_wo, *p_h;
    if (in_sizes[0] == 4096 && in_sizes[1] == 1048576) {
        p_h = d_in[0]; p_wk = d_in[1]; p_wo = d_in[2]; p_wq = d_in[3];
        p_wv = d_in[4]; p_hid = d_in[5]; p_pos = d_in[6];
    } else {
        p_hid = d_in[0]; p_pos = d_in[1]; p_wq = d_in[2]; p_wk = d_in[3];
        p_wv = d_in[4]; p_wo = d_in[5]; p_h = d_in[6];
    }
    const float* hidden = (const float*)p_hid;   // fp32 inputs (empirical)
    const int* pos_ids  = (const int*)p_pos;
    const float* Wq = (const float*)p_wq;
    const float* Wk = (const float*)p_wk;
    const float* Wv = (const float*)p_wv;
    const float* Wo = (const float*)p_wo;
    const float* Hsk = (const float*)p_h;
    float* out = (float*)d_out;   // FP32 output (reference returns fp32)

    // Workspace: 10,682,368 B total.
    float* Sq     = (float*)d_ws;                       // 32768 f
    float* Sk     = Sq + NH * NBLK * MSK;               // 8192 f
    int*   topkb  = (int*)(Sk + NKV * NBLK * MSK);      // 8192 i
    bf16*  kf     = (bf16*)(topkb + NH * NBLK * KTOP);  // 4,194,304 B
    bf16*  vf     = kf + (size_t)S_LEN * NKV * HD;      // 4,194,304 B
    bf16*  q_c    = vf + (size_t)S_LEN * NKV * HD;      // 1,048,576 B (CH x 2048)
    bf16*  attn_c = q_c + (size_t)CH * (NH * HD);       // 1,048,576 B

    // Upfront: K projection+rope+sketch (full S), V projection (full S).
    proj_rope_sketch<<<dim3(NKV, NBLK), 256, 0, stream>>>(
        hidden, Wk, pos_ids, Hsk, kf, Sk, NKV, 0);
    gemm_t<float, float, bf16><<<dim3((NKV * HD) / 64, S_LEN / 64), 256, 0, stream>>>(
        hidden, Wv, vf, NKV * HD, HID, 0);

    // Chunked: q proj+rope+sketch -> topk -> sparse attn -> O-projection.
    for (int c = 0; c < NCH; c++) {
        const int r0 = c * CH;
        proj_rope_sketch<<<dim3(NH, CH / 64), 256, 0, stream>>>(
            hidden, Wq, pos_ids, Hsk, q_c, Sq, NH, r0);
        topk_kernel<<<dim3(CH / 64, NH), 64, 0, stream>>>(Sq, Sk, topkb, r0 >> 6);
        attn_kernel<<<dim3(CH / 64, NH, 2), 256, 0, stream>>>(
            q_c, kf, vf, topkb, attn_c, r0);
        gemm_t<bf16, float, float><<<dim3(HID / 64, CH / 64), 256, 0, stream>>>(
            attn_c, Wo, out, HID, HID, r0);
    }
}

// Round 10
// 1751.593 us; speedup vs baseline: 5.8107x; 5.8107x over previous
//
#include <hip/hip_runtime.h>
#include <hip/hip_bf16.h>

// Problem constants (B=1)
#define S_LEN 4096
#define HID 2048
#define NH 16
#define NKV 4
#define HD 128        // D
#define MSK 32        // M (sketch dim)
#define KTOP 8
#define NBLK 64       // S/BLK
#define NEGV -1000000000.0f
#define SENT -3.0e38f

typedef __hip_bfloat16 bf16;
typedef __attribute__((ext_vector_type(8))) short short8;   // 8 bf16 (4 VGPR)
typedef __attribute__((ext_vector_type(4))) float f32x4;

// EMPIRICAL (R1-R9): inputs fp32, output fp32. Selection (sketch->topk) kept
// at fp32 end-to-end; smooth paths (q/k/v/attn staging, V/O GEMM) in bf16.

__device__ __forceinline__ unsigned short f2b(float v) {
    __hip_bfloat16 h = __float2bfloat16(v);
    return *reinterpret_cast<unsigned short*>(&h);
}
__device__ __forceinline__ float b2f(unsigned short u) {
    return __bfloat162float(*reinterpret_cast<__hip_bfloat16*>(&u));
}
__device__ __forceinline__ void stc(bf16* p, float v) { *p = __float2bfloat16(v); }
__device__ __forceinline__ void stc(float* p, float v) { *p = v; }

// ---------------------------------------------------------------------------
// FUSED projection + RoPE + block-sketch (fp32 selection path), v2:
// float4 loads, KCH=32, As/Ws aliased into Rt (LDS 51KB -> 3 blocks/CU).
// One block per (head h, row-block): global rows m0g..+63. Xout rows are
// (global - xbase). Sout indexed by GLOBAL block.
// ---------------------------------------------------------------------------
__global__ __launch_bounds__(256) void proj_rope_sketch(
    const float* __restrict__ A, const float* __restrict__ W,
    const int* __restrict__ pos_ids, const float* __restrict__ H,
    bf16* __restrict__ Xout, float* __restrict__ Sout,
    int nheads, int r0, int xbase) {
    const int h = blockIdx.x;
    const int m0g = r0 + blockIdx.y * 64;
    const int m0x = m0g - xbase;
    const int Nd = nheads * HD;
    const int t = threadIdx.x;
    const int tx = t & 31, ty = t >> 5;

    __shared__ float Rt[64 * 129];            // 33024B; holds As/Ws during GEMM
    __shared__ float Hs[128][33];
    __shared__ float red[32][9];
    float(*__restrict__ As)[68] = (float(*)[68])Rt;            // [32][68]
    float(*__restrict__ Ws)[132] = (float(*)[132])(Rt + 2176); // [32][132]

    float acc[8][4];
#pragma unroll
    for (int i = 0; i < 8; i++)
#pragma unroll
        for (int j = 0; j < 4; j++) acc[i][j] = 0.f;

    for (int k0 = 0; k0 < HID; k0 += 32) {
        __syncthreads();
        // stage A-tile 64x32 (float4)
#pragma unroll
        for (int i = 0; i < 2; i++) {
            int idx = t + i * 256;           // 512 float4
            int row = idx >> 3, f4 = idx & 7;
            const float4 v = *(const float4*)&A[(size_t)(m0g + row) * HID + k0 + f4 * 4];
            As[f4 * 4 + 0][row] = v.x; As[f4 * 4 + 1][row] = v.y;
            As[f4 * 4 + 2][row] = v.z; As[f4 * 4 + 3][row] = v.w;
        }
        // stage W-tile 32x128 (float4, aligned LDS f4 store)
#pragma unroll
        for (int i = 0; i < 4; i++) {
            int idx = t + i * 256;           // 1024 float4
            int kk = idx >> 5, n4 = idx & 31;
            *(float4*)&Ws[kk][n4 * 4] =
                *(const float4*)&W[(size_t)(k0 + kk) * Nd + h * HD + n4 * 4];
        }
        __syncthreads();
#pragma unroll
        for (int kk = 0; kk < 32; kk++) {
            float a[8], b[4];
#pragma unroll
            for (int i = 0; i < 8; i++) a[i] = As[kk][ty * 8 + i];
#pragma unroll
            for (int j = 0; j < 4; j++) b[j] = Ws[kk][tx * 4 + j];
#pragma unroll
            for (int i = 0; i < 8; i++)
#pragma unroll
                for (int j = 0; j < 4; j++) acc[i][j] += a[i] * b[j];
        }
    }
    __syncthreads();   // GEMM reads done; Rt region reusable

    // stage pre-rope fp32 tile
#pragma unroll
    for (int i = 0; i < 8; i++)
#pragma unroll
        for (int j = 0; j < 4; j++) Rt[(ty * 8 + i) * 129 + tx * 4 + j] = acc[i][j];
    __syncthreads();

    // RoPE in fp32
    float posr[8];
#pragma unroll
    for (int i = 0; i < 8; i++) posr[i] = (float)pos_ids[m0g + ty * 8 + i];
    float rp[8][4];
#pragma unroll
    for (int j = 0; j < 4; j++) {
        const int col = tx * 4 + j;
        const int jj = col & 63;
        const float invf = 1.0f / powf(10000.0f, (float)jj * (1.0f / 64.0f));
#pragma unroll
        for (int i = 0; i < 8; i++) {
            const int row = ty * 8 + i;
            float fr = posr[i] * invf;
            float c = cosf(fr), s = sinf(fr);
            float partner = Rt[row * 129 + (col ^ 64)];
            rp[i][j] = (col < 64) ? (acc[i][j] * c - partner * s)
                                  : (acc[i][j] * c + partner * s);
        }
    }
    __syncthreads();   // all partner reads done

    // roped fp32 -> Rt (sketch), bf16 -> global (packed 8B stores)
#pragma unroll
    for (int i = 0; i < 8; i++) {
        const int row = ty * 8 + i;
        ushort4 u;
        u.x = f2b(rp[i][0]); u.y = f2b(rp[i][1]);
        u.z = f2b(rp[i][2]); u.w = f2b(rp[i][3]);
#pragma unroll
        for (int j = 0; j < 4; j++) Rt[row * 129 + tx * 4 + j] = rp[i][j];
        *(ushort4*)&Xout[(size_t)(m0x + row) * Nd + h * HD + tx * 4] = u;
    }
    for (int e = t; e < 128 * 32; e += 256) Hs[e >> 5][e & 31] = H[e];
    __syncthreads();

    // sketch: (m=t&31, g=t>>5) sums rows g*8..+8; LDS reduce
    {
        const int m = t & 31, g = t >> 5;
        float s = 0.f;
        for (int r = g * 8; r < g * 8 + 8; r++) {
            float part = 0.f;
            for (int d = 0; d < 128; d++) part += Rt[r * 129 + d] * Hs[d][m];
            s += part;
        }
        red[m][g] = s;
    }
    __syncthreads();
    if (t < 32) {
        float s2 = 0.f;
#pragma unroll
        for (int i = 0; i < 8; i++) s2 += red[t][i];
        Sout[((size_t)h * NBLK + (m0g >> 6)) * MSK + t] = s2 * (1.0f / 64.0f);
    }
}

// ---------------------------------------------------------------------------
// MFMA bf16 GEMM: C[cRow0+m, n] = A[m,:] @ W[:,n]. 64x64 tile, 4 waves,
// mfma_f32_16x16x32_bf16. A fp32 (convert) or bf16 (direct); W fp32->bf16.
// Layouts (verified §3): A-frag A[m=lane&15][k=quad*8+j]; B-frag
// B[k=quad*8+j][n=lane&15]; C/D col=lane&15, row=quad*4+reg.
// ---------------------------------------------------------------------------
__device__ __forceinline__ void stage8(const float* p, unsigned short* dst) {
    const float4 a = *(const float4*)p;
    const float4 b = *(const float4*)(p + 4);
    ushort4 u0; u0.x = f2b(a.x); u0.y = f2b(a.y); u0.z = f2b(a.z); u0.w = f2b(a.w);
    ushort4 u1; u1.x = f2b(b.x); u1.y = f2b(b.y); u1.z = f2b(b.z); u1.w = f2b(b.w);
    *(ushort4*)dst = u0; *(ushort4*)(dst + 4) = u1;
}
__device__ __forceinline__ void stage8(const bf16* p, unsigned short* dst) {
    *(uint4*)dst = *(const uint4*)p;
}

template <typename AT, typename CT>
__global__ __launch_bounds__(256) void gemm_mfma(const AT* __restrict__ A,
                                                 const float* __restrict__ W,
                                                 CT* __restrict__ C,
                                                 int Ndim, int Kdim, int cRow0) {
    __shared__ unsigned short Al[64][40];   // [m][k], stride 80B (16B-aligned)
    __shared__ unsigned short Wl[64][40];   // [n][k] (transposed in staging)
    const int n0 = blockIdx.x * 64, m0 = blockIdx.y * 64;
    const int t = threadIdx.x;
    const int w = t >> 6, L = t & 63;
    const int lm = L & 15, lq = L >> 4;
    f32x4 acc[4];
#pragma unroll
    for (int nt = 0; nt < 4; nt++) acc[nt] = (f32x4){0.f, 0.f, 0.f, 0.f};

    for (int k0 = 0; k0 < Kdim; k0 += 32) {
        __syncthreads();
        {   // A: 64 rows x 32 k; thread -> (row = t>>2, 8-el chunk = t&3)
            int row = t >> 2, c8 = t & 3;
            stage8(&A[(size_t)(m0 + row) * Kdim + k0 + c8 * 8], &Al[row][c8 * 8]);
        }
        {   // W: 32 k x 64 n, transposed into Wl[n][k]
            int kk = t >> 3, n8 = (t & 7) * 8;
            const float4 a = *(const float4*)&W[(size_t)(k0 + kk) * Ndim + n0 + n8];
            const float4 b = *(const float4*)&W[(size_t)(k0 + kk) * Ndim + n0 + n8 + 4];
            Wl[n8 + 0][kk] = f2b(a.x); Wl[n8 + 1][kk] = f2b(a.y);
            Wl[n8 + 2][kk] = f2b(a.z); Wl[n8 + 3][kk] = f2b(a.w);
            Wl[n8 + 4][kk] = f2b(b.x); Wl[n8 + 5][kk] = f2b(b.y);
            Wl[n8 + 6][kk] = f2b(b.z); Wl[n8 + 7][kk] = f2b(b.w);
        }
        __syncthreads();
        short8 av = *(const short8*)&Al[w * 16 + lm][lq * 8];
#pragma unroll
        for (int nt = 0; nt < 4; nt++) {
            short8 bv = *(const short8*)&Wl[nt * 16 + lm][lq * 8];
            acc[nt] = __builtin_amdgcn_mfma_f32_16x16x32_bf16(av, bv, acc[nt], 0, 0, 0);
        }
    }
#pragma unroll
    for (int nt = 0; nt < 4; nt++)
#pragma unroll
        for (int r = 0; r < 4; r++) {
            int row = w * 16 + lq * 4 + r, col = nt * 16 + lm;
            stc(&C[(size_t)(cRow0 + m0 + row) * Ndim + n0 + col], acc[nt][r]);
        }
}

// ---------------------------------------------------------------------------
// Block scores + top-8 for q-blocks i = i0 + bx. Tie-break = lowest index.
// ---------------------------------------------------------------------------
__global__ __launch_bounds__(64) void topk_kernel(const float* __restrict__ Sq,
                                                  const float* __restrict__ Sk,
                                                  int* __restrict__ topk, int i0) {
    const int i = i0 + blockIdx.x, h = blockIdx.y, kv = h >> 2;
    const int j = threadIdx.x;
    __shared__ float vals[64];
    float v;
    if (j > i) v = NEGV;
    else if (j == i) v = 1e9f;
    else {
        v = 0.f;
        const float* sq = Sq + ((size_t)h * NBLK + i) * MSK;
        const float* sk = Sk + ((size_t)kv * NBLK + j) * MSK;
        for (int m = 0; m < MSK; m++) v += sq[m] * sk[m];
    }
    vals[j] = v;
    __syncthreads();
    if (j == 0) {
        for (int kk = 0; kk < KTOP; kk++) {
            float best = SENT; int bi = 0;
            for (int jj = 0; jj < 64; jj++)
                if (vals[jj] > best) { best = vals[jj]; bi = jj; }
            vals[bi] = SENT;
            topk[((size_t)h * NBLK + i) * KTOP + kk] = bi;
        }
    }
}

// ---------------------------------------------------------------------------
// Sparse attention, online softmax, rows [r0, r0+CHrows). q rows are
// (global - qbase) in qf. Writes attn_c chunk-local (rows - r0).
// Vectorized 16B bf16 staging.
// ---------------------------------------------------------------------------
__global__ __launch_bounds__(256) void attn_kernel(const bf16* __restrict__ qf,
                                                   const bf16* __restrict__ kf,
                                                   const bf16* __restrict__ vf,
                                                   const int* __restrict__ topk,
                                                   bf16* __restrict__ attn_c,
                                                   int r0, int qbase) {
    const int qbg = (r0 >> 6) + blockIdx.x;
    const int h = blockIdx.y, half = blockIdx.z;
    const int kvh = h >> 2;
    const int t = threadIdx.x;
    const int r = t & 31, g = t >> 5;
    __shared__ float Qs[32][129];
    __shared__ float KVs[64][129];
    __shared__ float Ss[32][65];
    __shared__ float mL[32], lL[32], aL[32];
    const int qrow0 = qbg * 64 + half * 32;

#pragma unroll
    for (int i = 0; i < 2; i++) {   // 32x128 bf16 = 512 uint4
        int idx = t + i * 256;
        int rr = idx >> 4, c8 = idx & 15;
        uint4 raw = *(const uint4*)&qf[(size_t)(qrow0 - qbase + rr) * (NH * HD) + h * HD + c8 * 8];
        const unsigned short* pu = (const unsigned short*)&raw;
#pragma unroll
        for (int j = 0; j < 8; j++)
            Qs[rr][c8 * 8 + j] = b2f(pu[j]) * 0.08838834764831845f;
    }
    if (t < 32) { mL[t] = -1.0e30f; lL[t] = 0.f; }
    float O[16];
#pragma unroll
    for (int c = 0; c < 16; c++) O[c] = 0.f;
    const int c0 = g * 16;
    const int* sel = topk + ((size_t)h * NBLK + qbg) * KTOP;

    for (int kb = 0; kb < KTOP; kb++) {
        const int blk = sel[kb] & 63;
        __syncthreads();   // (A)
#pragma unroll
        for (int i = 0; i < 4; i++) {   // 64x128 bf16 = 1024 uint4
            int idx = t + i * 256;
            int rr = idx >> 4, c8 = idx & 15;
            uint4 raw = *(const uint4*)&kf[(size_t)(blk * 64 + rr) * (NKV * HD) + kvh * HD + c8 * 8];
            const unsigned short* pu = (const unsigned short*)&raw;
#pragma unroll
            for (int j = 0; j < 8; j++) KVs[rr][c8 * 8 + j] = b2f(pu[j]);
        }
        __syncthreads();   // (B)
        float sc[8];
#pragma unroll
        for (int jj = 0; jj < 8; jj++) sc[jj] = 0.f;
        for (int d = 0; d < 128; d++) {
            float qv = Qs[r][d];
#pragma unroll
            for (int jj = 0; jj < 8; jj++) sc[jj] += qv * KVs[g * 8 + jj][d];
        }
        const int qpos = qrow0 + r;
#pragma unroll
        for (int jj = 0; jj < 8; jj++) {
            int j = g * 8 + jj;
            int kpos = blk * 64 + j;
            Ss[r][j] = (kpos <= qpos) ? sc[jj] : NEGV;
        }
        __syncthreads();   // (C)
#pragma unroll
        for (int i = 0; i < 4; i++) {   // stage V over K
            int idx = t + i * 256;
            int rr = idx >> 4, c8 = idx & 15;
            uint4 raw = *(const uint4*)&vf[(size_t)(blk * 64 + rr) * (NKV * HD) + kvh * HD + c8 * 8];
            const unsigned short* pu = (const unsigned short*)&raw;
#pragma unroll
            for (int j = 0; j < 8; j++) KVs[rr][c8 * 8 + j] = b2f(pu[j]);
        }
        if (t < 32) {
            const int row = t;
            float mb = SENT;
            for (int j = 0; j < 64; j++) mb = fmaxf(mb, Ss[row][j]);
            float mnew = fmaxf(mL[row], mb);
            float al = expf(mL[row] - mnew);
            float sum = 0.f;
            for (int j = 0; j < 64; j++) {
                float p = expf(Ss[row][j] - mnew);
                Ss[row][j] = p;
                sum += p;
            }
            lL[row] = lL[row] * al + sum;
            mL[row] = mnew;
            aL[row] = al;
        }
        __syncthreads();   // (D)
        float al = aL[r];
#pragma unroll
        for (int c = 0; c < 16; c++) O[c] *= al;
        for (int j = 0; j < 64; j++) {
            float p = Ss[r][j];
#pragma unroll
            for (int c = 0; c < 16; c++) O[c] += p * KVs[j][c0 + c];
        }
    }
    float inv_l = 1.0f / lL[r];
    bf16* dst = &attn_c[(size_t)(qrow0 - r0 + r) * (NH * HD) + h * HD + c0];
#pragma unroll
    for (int c4 = 0; c4 < 4; c4++) {
        ushort4 u;
        u.x = f2b(O[c4 * 4 + 0] * inv_l); u.y = f2b(O[c4 * 4 + 1] * inv_l);
        u.z = f2b(O[c4 * 4 + 2] * inv_l); u.w = f2b(O[c4 * 4 + 3] * inv_l);
        *(ushort4*)&dst[c4 * 4] = u;
    }
}

// ---------------------------------------------------------------------------
extern "C" void kernel_launch(void* const* d_in, const int* in_sizes, int n_in,
                              void* d_out, int out_size, void* d_ws, size_t ws_size,
                              hipStream_t stream) {
    const void *p_hid, *p_pos, *p_wq, *p_wk, *p_wv, *p_wo, *p_h;
    if (in_sizes[0] == 4096 && in_sizes[1] == 1048576) {
        p_h = d_in[0]; p_wk = d_in[1]; p_wo = d_in[2]; p_wq = d_in[3];
        p_wv = d_in[4]; p_hid = d_in[5]; p_pos = d_in[6];
    } else {
        p_hid = d_in[0]; p_pos = d_in[1]; p_wq = d_in[2]; p_wk = d_in[3];
        p_wv = d_in[4]; p_wo = d_in[5]; p_h = d_in[6];
    }
    const float* hidden = (const float*)p_hid;
    const int* pos_ids  = (const int*)p_pos;
    const float* Wq = (const float*)p_wq;
    const float* Wk = (const float*)p_wk;
    const float* Wv = (const float*)p_wv;
    const float* Wo = (const float*)p_wo;
    const float* Hsk = (const float*)p_h;
    float* out = (float*)d_out;

    // ws layout (bytes): Sq 131072 | Sk 32768 | topk 32768 | kf 4M | vf 4M |
    //   full: qf 16.78M | attn_c 4M  (total 29,556,736)
    //   fallback (proven 10.68MB): q_c 1M | attn_c 1M
    char* base = (char*)d_ws;
    float* Sq    = (float*)base;
    float* Sk    = (float*)(base + 131072);
    int*   topkb = (int*)(base + 163840);
    bf16*  kf    = (bf16*)(base + 196608);
    bf16*  vf    = (bf16*)(base + 196608 + 4194304);
    bf16*  qbuf  = (bf16*)(base + 196608 + 8388608);
    const size_t FULL_NEED = 29556736;
    const bool full = (ws_size >= FULL_NEED);

    // K projection+rope+sketch (full S), V projection (MFMA, full S).
    proj_rope_sketch<<<dim3(NKV, NBLK), 256, 0, stream>>>(
        hidden, Wk, pos_ids, Hsk, kf, Sk, NKV, 0, 0);
    gemm_mfma<float, bf16><<<dim3((NKV * HD) / 64, S_LEN / 64), 256, 0, stream>>>(
        hidden, Wv, vf, NKV * HD, HID, 0);

    if (full) {
        bf16* attn_c = qbuf + (size_t)S_LEN * NH * HD;     // 4MB, CH=1024
        // Q proj (full S, one launch), topk (one launch)
        proj_rope_sketch<<<dim3(NH, NBLK), 256, 0, stream>>>(
            hidden, Wq, pos_ids, Hsk, qbuf, Sq, NH, 0, 0);
        topk_kernel<<<dim3(NBLK, NH), 64, 0, stream>>>(Sq, Sk, topkb, 0);
        for (int c = 0; c < 4; c++) {
            const int r0 = c * 1024;
            attn_kernel<<<dim3(16, NH, 2), 256, 0, stream>>>(
                qbuf, kf, vf, topkb, attn_c, r0, 0);
            gemm_mfma<bf16, float><<<dim3(HID / 64, 16), 256, 0, stream>>>(
                attn_c, Wo, out, HID, HID, r0);
        }
    } else {
        bf16* attn_c = qbuf + (size_t)256 * NH * HD;       // 1MB, CH=256
        for (int c = 0; c < 16; c++) {
            const int r0 = c * 256;
            proj_rope_sketch<<<dim3(NH, 4), 256, 0, stream>>>(
                hidden, Wq, pos_ids, Hsk, qbuf, Sq, NH, r0, r0);
            topk_kernel<<<dim3(4, NH), 64, 0, stream>>>(Sq, Sk, topkb, r0 >> 6);
            attn_kernel<<<dim3(4, NH, 2), 256, 0, stream>>>(
                qbuf, kf, vf, topkb, attn_c, r0, r0);
            gemm_mfma<bf16, float><<<dim3(HID / 64, 4), 256, 0, stream>>>(
                attn_c, Wo, out, HID, HID, r0);
        }
    }
}